// Round 4
// baseline (427.644 us; speedup 1.0000x reference)
//
#include <hip/hip_runtime.h>
#include <hip/hip_bf16.h>
#include <math.h>

// ExpertPool: B=2,N=1024 -> T=2048 tokens, D=768, E=8, H=3072, top-K=2
#define T_TOK 2048
#define DIM   768
#define NEXP  8
#define HDIM  3072
#define MAXP  (T_TOK * 2)   // exactly 4096 (token,expert) pairs
#define LDST  40            // padded stride for fallback path only
#define NTILE_MAX 40        // sum ceil(cnt_e/128) <= 39

typedef __attribute__((ext_vector_type(8))) short bfrag;   // 8 bf16 (4 VGPRs)
typedef __attribute__((ext_vector_type(4))) float f32x4;   // MFMA C/D

__device__ __forceinline__ unsigned short f2bf(float f) {
  union { float f; unsigned int u; } x; x.f = f;
  unsigned int r = x.u + 0x7fffu + ((x.u >> 16) & 1u);  // RNE
  return (unsigned short)(r >> 16);
}

// async 16B global->LDS (m97: the 874-TF staging path). LDS dest must be
// wave-uniform base + lane*16 -> LDS layout contiguous in lane order, NO pad.
__device__ __forceinline__ void async16(const void* g, void* l) {
  __builtin_amdgcn_global_load_lds(
      (const __attribute__((address_space(1))) void*)g,
      (__attribute__((address_space(3))) void*)l, 16, 0, 0);
}

// ---------------- routing + tile table + token->pair map ----------------
__global__ void k_route(const float* __restrict__ disp,
                        const float* __restrict__ comb,
                        int* __restrict__ meta,        // [0..7]=cnt [8..15]=off [16]=ntiles [17..56]=tiles
                        float* __restrict__ row_comb,
                        int* __restrict__ row_token,
                        int* __restrict__ tok2pair) {  // (T_TOK,2)
  __shared__ int s_cnt[NEXP], s_off[NEXP], s_cur[NEXP];
  __shared__ int s_tn[T_TOK];
  int tid = threadIdx.x;
  if (tid < NEXP) s_cnt[tid] = 0;
  for (int t = tid; t < T_TOK; t += 256) s_tn[t] = 0;
  __syncthreads();
  for (int t = tid; t < T_TOK; t += 256)
    for (int e = 0; e < NEXP; ++e)
      if (disp[t * NEXP + e] > 0.f) atomicAdd(&s_cnt[e], 1);
  __syncthreads();
  if (tid == 0) {
    int acc = 0;
    for (int e = 0; e < NEXP; ++e) { s_off[e] = acc; acc += s_cnt[e]; }
  }
  __syncthreads();
  if (tid < NEXP) {
    s_cur[tid] = s_off[tid];
    meta[tid] = s_cnt[tid];
    meta[NEXP + tid] = s_off[tid];
  }
  __syncthreads();
  for (int t = tid; t < T_TOK; t += 256)
    for (int e = 0; e < NEXP; ++e)
      if (disp[t * NEXP + e] > 0.f) {
        int p = atomicAdd(&s_cur[e], 1);
        row_token[p] = t;
        row_comb[p] = comb[t * NEXP + e];
        int sl = atomicAdd(&s_tn[t], 1);
        tok2pair[t * 2 + sl] = p;
      }
  __syncthreads();
  if (tid == 0) {
    int nt = 0;
    for (int e = 0; e < NEXP; ++e)
      for (int m0 = 0; m0 < s_cnt[e]; m0 += 128)
        meta[17 + nt++] = (e << 16) | (m0 >> 7);
    meta[16] = nt;
  }
}

// -------- one-shot fp32->bf16 of X, Wg, Wv, Wo (segmented grid-stride) --------
#define CH_X   196608                 // 1572864/8
#define CH_W   2359296                // 18874368/8
__global__ void k_cvt(const float* __restrict__ X, const float* __restrict__ Wg,
                      const float* __restrict__ Wv, const float* __restrict__ Wo,
                      unsigned short* __restrict__ Xb, unsigned short* __restrict__ Wgb,
                      unsigned short* __restrict__ Wvb, unsigned short* __restrict__ Wob) {
  int c = blockIdx.x * 256 + threadIdx.x;  // one 8-elem chunk
  const float* src; unsigned short* dst; size_t idx;
  if (c < CH_X)                { src = X;  dst = Xb;  idx = (size_t)c * 8; }
  else if (c < CH_X + CH_W)    { src = Wg; dst = Wgb; idx = (size_t)(c - CH_X) * 8; }
  else if (c < CH_X + 2*CH_W)  { src = Wv; dst = Wvb; idx = (size_t)(c - CH_X - CH_W) * 8; }
  else                         { src = Wo; dst = Wob; idx = (size_t)(c - CH_X - 2*CH_W) * 8; }
  float4 a = *(const float4*)(src + idx);
  float4 b = *(const float4*)(src + idx + 4);
  unsigned short r[8];
  r[0]=f2bf(a.x); r[1]=f2bf(a.y); r[2]=f2bf(a.z); r[3]=f2bf(a.w);
  r[4]=f2bf(b.x); r[5]=f2bf(b.y); r[6]=f2bf(b.z); r[7]=f2bf(b.w);
  *(uint4*)(dst + idx) = *(uint4*)r;
}

// ------- GEMM 1 fused (async path): u = gelu(X@Wg^T)*(X@Wv^T) -> bf16 -------
__global__ __launch_bounds__(256, 2) void k_gemm_gv_a(
    const unsigned short* __restrict__ Xb,   // (T_TOK, DIM) bf16
    const unsigned short* __restrict__ Wgb,  // (NEXP*HDIM, DIM) bf16
    const unsigned short* __restrict__ Wvb,
    const int* __restrict__ meta,
    const int* __restrict__ row_token,
    unsigned short* __restrict__ ubuf)       // (MAXP, HDIM) bf16
{
  int blk = blockIdx.x;
  int t = blk % NTILE_MAX;
  int nt = blk / NTILE_MAX;
  if (t >= meta[16]) return;
  int tv = meta[17 + t];
  int e = tv >> 16, m0 = (tv & 0xffff) << 7;
  int cnt = meta[e], off = meta[NEXP + e];
  int n0 = nt * 128;

  __shared__ unsigned short As[128 * 32];
  __shared__ unsigned short Bgs[128 * 32];
  __shared__ unsigned short Bvs[128 * 32];

  int tid = threadIdx.x;
  int wid = tid >> 6, lane = tid & 63;
  int wm = (wid >> 1) * 64, wn = (wid & 1) * 64;
  int lr = lane & 15, quad = lane >> 4;

  // per-round gathered A row and chunk geometry (rows fixed across K-steps)
  int a_tok[2]; int sub[2]; int brow[2];
#pragma unroll
  for (int r = 0; r < 2; ++r) {
    int c = tid + 256 * r;
    int row = c >> 2; sub[r] = c & 3; brow[r] = row;
    int gr = m0 + row; if (gr >= cnt) gr = cnt - 1;
    a_tok[r] = row_token[off + gr];
  }

  const unsigned short* WgB = Wgb + (size_t)e * HDIM * DIM;
  const unsigned short* WvB = Wvb + (size_t)e * HDIM * DIM;

  f32x4 zero4 = {0.f, 0.f, 0.f, 0.f};
  f32x4 accg[4][4], accv[4][4];
#pragma unroll
  for (int i = 0; i < 4; ++i)
#pragma unroll
    for (int j = 0; j < 4; ++j) { accg[i][j] = zero4; accv[i][j] = zero4; }

  for (int k0 = 0; k0 < DIM; k0 += 32) {
    __syncthreads();
#pragma unroll
    for (int r = 0; r < 2; ++r) {
      int c = tid + 256 * r;
      async16(Xb + (size_t)a_tok[r] * DIM + k0 + sub[r] * 8, &As[c * 8]);
      async16(WgB + (size_t)(n0 + brow[r]) * DIM + k0 + sub[r] * 8, &Bgs[c * 8]);
      async16(WvB + (size_t)(n0 + brow[r]) * DIM + k0 + sub[r] * 8, &Bvs[c * 8]);
    }
    __syncthreads();
    bfrag a[4], bg[4], bv[4];
#pragma unroll
    for (int i = 0; i < 4; ++i)
      a[i] = *(const bfrag*)(&As[(wm + i * 16 + lr) * 32 + quad * 8]);
#pragma unroll
    for (int j = 0; j < 4; ++j) {
      bg[j] = *(const bfrag*)(&Bgs[(wn + j * 16 + lr) * 32 + quad * 8]);
      bv[j] = *(const bfrag*)(&Bvs[(wn + j * 16 + lr) * 32 + quad * 8]);
    }
#pragma unroll
    for (int i = 0; i < 4; ++i)
#pragma unroll
      for (int j = 0; j < 4; ++j) {
        accg[i][j] = __builtin_amdgcn_mfma_f32_16x16x32_bf16(a[i], bg[j], accg[i][j], 0, 0, 0);
        accv[i][j] = __builtin_amdgcn_mfma_f32_16x16x32_bf16(a[i], bv[j], accv[i][j], 0, 0, 0);
      }
  }

#pragma unroll
  for (int i = 0; i < 4; ++i)
#pragma unroll
    for (int rg = 0; rg < 4; ++rg) {
      int gr = m0 + wm + i * 16 + quad * 4 + rg;
      if (gr < cnt) {
        size_t base = (size_t)(off + gr) * HDIM + n0 + wn;
#pragma unroll
        for (int j = 0; j < 4; ++j) {
          float g = accg[i][j][rg];
          float v = accv[i][j][rg];
          float u = 0.5f * g * (1.0f + erff(g * 0.70710678118654752f)) * v;
          ubuf[base + j * 16 + lr] = f2bf(u);
        }
      }
    }
}

// ------- GEMM 2 (async path): u @ Wo^T -> w-scaled partials, split-K x4 -------
__global__ __launch_bounds__(256, 2) void k_gemm_out_a(
    const unsigned short* __restrict__ U,    // (MAXP, HDIM) bf16
    const unsigned short* __restrict__ Wob,  // (NEXP*DIM, HDIM) bf16
    const float* __restrict__ scale,
    const int* __restrict__ meta,
    const float* __restrict__ row_comb,
    float* __restrict__ partial)             // (4, MAXP, DIM)
{
  int blk = blockIdx.x;                      // 40*6*4 = 960
  int t = blk % NTILE_MAX;
  int rest = blk / NTILE_MAX;
  int nt = rest % 6;
  int ks = rest / 6;
  if (t >= meta[16]) return;
  int tv = meta[17 + t];
  int e = tv >> 16, m0 = (tv & 0xffff) << 7;
  int cnt = meta[e], off = meta[NEXP + e];
  int n0 = nt * 128;
  int kbase = ks * (HDIM / 4);

  __shared__ unsigned short As[128 * 32];
  __shared__ unsigned short Bs[128 * 32];

  int tid = threadIdx.x;
  int wid = tid >> 6, lane = tid & 63;
  int wm = (wid >> 1) * 64, wn = (wid & 1) * 64;
  int lr = lane & 15, quad = lane >> 4;

  int a_grow[2]; int sub[2]; int brow[2];
#pragma unroll
  for (int r = 0; r < 2; ++r) {
    int c = tid + 256 * r;
    int row = c >> 2; sub[r] = c & 3; brow[r] = row;
    int gr = m0 + row; if (gr >= cnt) gr = cnt - 1;
    a_grow[r] = off + gr;
  }

  const unsigned short* WoB = Wob + (size_t)e * DIM * HDIM;

  f32x4 zero4 = {0.f, 0.f, 0.f, 0.f};
  f32x4 acc[4][4];
#pragma unroll
  for (int i = 0; i < 4; ++i)
#pragma unroll
    for (int j = 0; j < 4; ++j) acc[i][j] = zero4;

  for (int kk = 0; kk < HDIM / 4; kk += 32) {
    int k0 = kbase + kk;
    __syncthreads();
#pragma unroll
    for (int r = 0; r < 2; ++r) {
      int c = tid + 256 * r;
      async16(U + (size_t)a_grow[r] * HDIM + k0 + sub[r] * 8, &As[c * 8]);
      async16(WoB + (size_t)(n0 + brow[r]) * HDIM + k0 + sub[r] * 8, &Bs[c * 8]);
    }
    __syncthreads();
    bfrag a[4], b[4];
#pragma unroll
    for (int i = 0; i < 4; ++i)
      a[i] = *(const bfrag*)(&As[(wm + i * 16 + lr) * 32 + quad * 8]);
#pragma unroll
    for (int j = 0; j < 4; ++j)
      b[j] = *(const bfrag*)(&Bs[(wn + j * 16 + lr) * 32 + quad * 8]);
#pragma unroll
    for (int i = 0; i < 4; ++i)
#pragma unroll
      for (int j = 0; j < 4; ++j)
        acc[i][j] = __builtin_amdgcn_mfma_f32_16x16x32_bf16(a[i], b[j], acc[i][j], 0, 0, 0);
  }

  float sc = scale[e];
#pragma unroll
  for (int i = 0; i < 4; ++i)
#pragma unroll
    for (int rg = 0; rg < 4; ++rg) {
      int gr = m0 + wm + i * 16 + quad * 4 + rg;
      if (gr < cnt) {
        int grow = off + gr;
        float w = row_comb[grow] * sc;
        float* pb = partial + ((size_t)ks * MAXP + grow) * DIM + n0 + wn;
#pragma unroll
        for (int j = 0; j < 4; ++j)
          pb[j * 16 + lr] = acc[i][j][rg] * w;
      }
    }
}

// ---------------- combine: out[t] = sum over 2 pairs x 4 K-splits ----------------
__global__ void k_combine(const float* __restrict__ partial,
                          const int* __restrict__ tok2pair,
                          float* __restrict__ out) {
  int idx = blockIdx.x * 256 + threadIdx.x;
  int t = idx / 192, d4 = idx % 192;
  int p0 = tok2pair[t * 2], p1 = tok2pair[t * 2 + 1];
  float sx = 0.f, sy = 0.f, sz = 0.f, sw = 0.f;
#pragma unroll
  for (int ks = 0; ks < 4; ++ks) {
    float4 a = *(const float4*)(partial + ((size_t)ks * MAXP + p0) * DIM + d4 * 4);
    float4 b = *(const float4*)(partial + ((size_t)ks * MAXP + p1) * DIM + d4 * 4);
    sx += a.x + b.x; sy += a.y + b.y; sz += a.z + b.z; sw += a.w + b.w;
  }
  float4 r; r.x = sx; r.y = sy; r.z = sz; r.w = sw;
  *(float4*)(out + (size_t)t * DIM + d4 * 4) = r;
}

// ================= fallback path (round-3, fp32 inline convert) =================
__global__ void k_xbf(const float* __restrict__ X, unsigned short* __restrict__ Xb) {
  size_t i = ((size_t)blockIdx.x * 256 + threadIdx.x) * 8;
  float4 a = *(const float4*)(X + i);
  float4 b = *(const float4*)(X + i + 4);
  unsigned short r[8];
  r[0]=f2bf(a.x); r[1]=f2bf(a.y); r[2]=f2bf(a.z); r[3]=f2bf(a.w);
  r[4]=f2bf(b.x); r[5]=f2bf(b.y); r[6]=f2bf(b.z); r[7]=f2bf(b.w);
  *(uint4*)(Xb + i) = *(uint4*)r;
}

__global__ __launch_bounds__(256, 2) void k_gemm_gv_f(
    const unsigned short* __restrict__ Xb, const float* __restrict__ Wg,
    const float* __restrict__ Wv, const int* __restrict__ meta,
    const int* __restrict__ row_token, unsigned short* __restrict__ ubuf) {
  int blk = blockIdx.x;
  int t = blk % NTILE_MAX;
  int nt = blk / NTILE_MAX;
  if (t >= meta[16]) return;
  int tv = meta[17 + t];
  int e = tv >> 16, m0 = (tv & 0xffff) << 7;
  int cnt = meta[e], off = meta[NEXP + e];
  int n0 = nt * 128;
  __shared__ unsigned short As[128 * LDST];
  __shared__ unsigned short Bgs[128 * LDST];
  __shared__ unsigned short Bvs[128 * LDST];
  int tid = threadIdx.x;
  int wid = tid >> 6, lane = tid & 63;
  int wm = (wid >> 1) * 64, wn = (wid & 1) * 64;
  int lr = lane & 15, quad = lane >> 4;
  int a_tok[2];
#pragma unroll
  for (int r = 0; r < 2; ++r) {
    int row = (tid + 256 * r) >> 2;
    int gr = m0 + row; if (gr >= cnt) gr = cnt - 1;
    a_tok[r] = row_token[off + gr];
  }
  const float* Wgb = Wg + (size_t)e * HDIM * DIM;
  const float* Wvb = Wv + (size_t)e * HDIM * DIM;
  f32x4 zero4 = {0.f,0.f,0.f,0.f};
  f32x4 accg[4][4], accv[4][4];
#pragma unroll
  for (int i = 0; i < 4; ++i)
#pragma unroll
    for (int j = 0; j < 4; ++j) { accg[i][j] = zero4; accv[i][j] = zero4; }
  for (int k0 = 0; k0 < DIM; k0 += 32) {
    __syncthreads();
#pragma unroll
    for (int r = 0; r < 2; ++r) {
      int c = tid + 256 * r;
      int row = c >> 2, s4 = c & 3;
      uint4 av = *(const uint4*)(Xb + (size_t)a_tok[r] * DIM + k0 + s4 * 8);
      *(uint4*)(&As[row * LDST + s4 * 8]) = av;
    }
#pragma unroll
    for (int r = 0; r < 4; ++r) {
      int c = tid + 256 * r;
      int row = c >> 3, c4 = c & 7;
      float4 gv = *(const float4*)(Wgb + (size_t)(n0 + row) * DIM + k0 + c4 * 4);
      ushort4 gp; gp.x=f2bf(gv.x); gp.y=f2bf(gv.y); gp.z=f2bf(gv.z); gp.w=f2bf(gv.w);
      *(ushort4*)(&Bgs[row * LDST + c4 * 4]) = gp;
      float4 vv = *(const float4*)(Wvb + (size_t)(n0 + row) * DIM + k0 + c4 * 4);
      ushort4 vp; vp.x=f2bf(vv.x); vp.y=f2bf(vv.y); vp.z=f2bf(vv.z); vp.w=f2bf(vv.w);
      *(ushort4*)(&Bvs[row * LDST + c4 * 4]) = vp;
    }
    __syncthreads();
    bfrag a[4], bg[4], bv[4];
#pragma unroll
    for (int i = 0; i < 4; ++i)
      a[i] = *(const bfrag*)(&As[(wm + i * 16 + lr) * LDST + quad * 8]);
#pragma unroll
    for (int j = 0; j < 4; ++j) {
      bg[j] = *(const bfrag*)(&Bgs[(wn + j * 16 + lr) * LDST + quad * 8]);
      bv[j] = *(const bfrag*)(&Bvs[(wn + j * 16 + lr) * LDST + quad * 8]);
    }
#pragma unroll
    for (int i = 0; i < 4; ++i)
#pragma unroll
      for (int j = 0; j < 4; ++j) {
        accg[i][j] = __builtin_amdgcn_mfma_f32_16x16x32_bf16(a[i], bg[j], accg[i][j], 0, 0, 0);
        accv[i][j] = __builtin_amdgcn_mfma_f32_16x16x32_bf16(a[i], bv[j], accv[i][j], 0, 0, 0);
      }
  }
#pragma unroll
  for (int i = 0; i < 4; ++i)
#pragma unroll
    for (int rg = 0; rg < 4; ++rg) {
      int gr = m0 + wm + i * 16 + quad * 4 + rg;
      if (gr < cnt) {
        size_t base = (size_t)(off + gr) * HDIM + n0 + wn;
#pragma unroll
        for (int j = 0; j < 4; ++j) {
          float g = accg[i][j][rg];
          float v = accv[i][j][rg];
          float u = 0.5f * g * (1.0f + erff(g * 0.70710678118654752f)) * v;
          ubuf[base + j * 16 + lr] = f2bf(u);
        }
      }
    }
}

__global__ __launch_bounds__(256, 2) void k_gemm_out_f(
    const unsigned short* __restrict__ U, const float* __restrict__ Wo,
    const float* __restrict__ scale, const int* __restrict__ meta,
    const int* __restrict__ row_token, const float* __restrict__ row_comb,
    float* __restrict__ partial, float* __restrict__ out, int mode) {
  int blk = blockIdx.x;
  int t = blk % NTILE_MAX;
  int rest = blk / NTILE_MAX;
  int nt = rest % 6;
  int ks = rest / 6;
  if (t >= meta[16]) return;
  int tv = meta[17 + t];
  int e = tv >> 16, m0 = (tv & 0xffff) << 7;
  int cnt = meta[e], off = meta[NEXP + e];
  int n0 = nt * 128;
  int kbase = ks * (HDIM / 4);
  __shared__ unsigned short As[128 * LDST];
  __shared__ unsigned short Bs[128 * LDST];
  int tid = threadIdx.x;
  int wid = tid >> 6, lane = tid & 63;
  int wm = (wid >> 1) * 64, wn = (wid & 1) * 64;
  int lr = lane & 15, quad = lane >> 4;
  int a_grow[2];
#pragma unroll
  for (int r = 0; r < 2; ++r) {
    int row = (tid + 256 * r) >> 2;
    int gr = m0 + row; if (gr >= cnt) gr = cnt - 1;
    a_grow[r] = off + gr;
  }
  const float* Wb = Wo + (size_t)e * DIM * HDIM;
  f32x4 zero4 = {0.f,0.f,0.f,0.f};
  f32x4 acc[4][4];
#pragma unroll
  for (int i = 0; i < 4; ++i)
#pragma unroll
    for (int j = 0; j < 4; ++j) acc[i][j] = zero4;
  for (int kk = 0; kk < HDIM / 4; kk += 32) {
    int k0 = kbase + kk;
    __syncthreads();
#pragma unroll
    for (int r = 0; r < 2; ++r) {
      int c = tid + 256 * r;
      int row = c >> 2, s4 = c & 3;
      uint4 av = *(const uint4*)(U + (size_t)a_grow[r] * HDIM + k0 + s4 * 8);
      *(uint4*)(&As[row * LDST + s4 * 8]) = av;
    }
#pragma unroll
    for (int r = 0; r < 4; ++r) {
      int c = tid + 256 * r;
      int row = c >> 3, c4 = c & 7;
      float4 bvv = *(const float4*)(Wb + (size_t)(n0 + row) * HDIM + k0 + c4 * 4);
      ushort4 bp; bp.x=f2bf(bvv.x); bp.y=f2bf(bvv.y); bp.z=f2bf(bvv.z); bp.w=f2bf(bvv.w);
      *(ushort4*)(&Bs[row * LDST + c4 * 4]) = bp;
    }
    __syncthreads();
    bfrag a[4], b[4];
#pragma unroll
    for (int i = 0; i < 4; ++i)
      a[i] = *(const bfrag*)(&As[(wm + i * 16 + lr) * LDST + quad * 8]);
#pragma unroll
    for (int j = 0; j < 4; ++j)
      b[j] = *(const bfrag*)(&Bs[(wn + j * 16 + lr) * LDST + quad * 8]);
#pragma unroll
    for (int i = 0; i < 4; ++i)
#pragma unroll
      for (int j = 0; j < 4; ++j)
        acc[i][j] = __builtin_amdgcn_mfma_f32_16x16x32_bf16(a[i], b[j], acc[i][j], 0, 0, 0);
  }
  float sc = scale[e];
#pragma unroll
  for (int i = 0; i < 4; ++i)
#pragma unroll
    for (int rg = 0; rg < 4; ++rg) {
      int gr = m0 + wm + i * 16 + quad * 4 + rg;
      if (gr < cnt) {
        int grow = off + gr;
        float w = row_comb[grow] * sc;
        if (mode == 0) {
          float* pb = partial + ((size_t)ks * MAXP + grow) * DIM + n0 + wn;
#pragma unroll
          for (int j = 0; j < 4; ++j) pb[j * 16 + lr] = acc[i][j][rg] * w;
        } else {
          int tok = row_token[grow];
          float* ob = out + (size_t)tok * DIM + n0 + wn;
#pragma unroll
          for (int j = 0; j < 4; ++j) atomicAdd(ob + j * 16 + lr, acc[i][j][rg] * w);
        }
      }
    }
}

extern "C" void kernel_launch(void* const* d_in, const int* in_sizes, int n_in,
                              void* d_out, int out_size, void* d_ws, size_t ws_size,
                              hipStream_t stream) {
  const float* tokens = (const float*)d_in[0];
  const float* disp   = (const float*)d_in[1];
  const float* comb   = (const float*)d_in[2];
  const float* Wg     = (const float*)d_in[3];
  const float* Wv     = (const float*)d_in[4];
  const float* Wo     = (const float*)d_in[5];
  const float* scale  = (const float*)d_in[6];
  float* out = (float*)d_out;

  char* ws = (char*)d_ws;
  int*   meta      = (int*)ws;
  int*   row_token = (int*)(ws + 16384);
  float* row_comb  = (float*)(ws + 32768);
  int*   tok2pair  = (int*)(ws + 49152);

  const size_t MB = 1ull << 20;
  // new path layout: Xb@1M(3M) ubuf@4M(24M) partial@28M(48M, overlays dead Wgb/Wvb after gv)
  //                  Wgb@28M? NO -> Wgb@28M..64M, Wvb@64M..100M, Wob@100M..136M; partial@28M..76M
  unsigned short* Xb   = (unsigned short*)(ws + 1 * MB);
  unsigned short* ubuf = (unsigned short*)(ws + 4 * MB);
  unsigned short* Wgb  = (unsigned short*)(ws + 28 * MB);
  unsigned short* Wvb  = (unsigned short*)(ws + 64 * MB);
  unsigned short* Wob  = (unsigned short*)(ws + 100 * MB);
  float* partial_new   = (float*)(ws + 28 * MB);

  hipLaunchKernelGGL(k_route, dim3(1), dim3(256), 0, stream,
                     disp, comb, meta, row_comb, row_token, tok2pair);

  if (ws_size >= 136 * MB) {
    hipLaunchKernelGGL(k_cvt, dim3((CH_X + 3 * CH_W) / 256), dim3(256), 0, stream,
                       tokens, Wg, Wv, Wo, Xb, Wgb, Wvb, Wob);
    hipLaunchKernelGGL(k_gemm_gv_a, dim3(NTILE_MAX * 24), dim3(256), 0, stream,
                       Xb, Wgb, Wvb, meta, row_token, ubuf);
    hipLaunchKernelGGL(k_gemm_out_a, dim3(NTILE_MAX * 6 * 4), dim3(256), 0, stream,
                       ubuf, Wob, scale, meta, row_comb, partial_new);
    hipLaunchKernelGGL(k_combine, dim3((T_TOK * DIM / 4) / 256), dim3(256), 0, stream,
                       partial_new, tok2pair, out);
  } else {
    // fallback: round-3 verified path
    unsigned short* Xb2   = (unsigned short*)(ws + 1 * MB);
    unsigned short* ubuf2 = (unsigned short*)(ws + 5 * MB);
    float* partial_old    = (float*)(ws + 32 * MB);
    size_t need_partial = 32 * MB + (size_t)4 * MAXP * DIM * sizeof(float);
    int mode = (ws_size >= need_partial) ? 0 : 1;
    hipLaunchKernelGGL(k_xbf, dim3((T_TOK * DIM) / (256 * 8)), dim3(256), 0, stream, tokens, Xb2);
    hipLaunchKernelGGL(k_gemm_gv_f, dim3(NTILE_MAX * 24), dim3(256), 0, stream,
                       Xb2, Wg, Wv, meta, row_token, ubuf2);
    if (mode == 1)
      hipMemsetAsync(d_out, 0, (size_t)out_size * sizeof(float), stream);
    hipLaunchKernelGGL(k_gemm_out_f, dim3(NTILE_MAX * 6 * 4), dim3(256), 0, stream,
                       ubuf2, Wo, scale, meta, row_token, row_comb, partial_old, out, mode);
    if (mode == 0)
      hipLaunchKernelGGL(k_combine, dim3((T_TOK * DIM / 4) / 256), dim3(256), 0, stream,
                         partial_old, tok2pair, out);
  }
}